// Round 1
// baseline (1348.614 us; speedup 1.0000x reference)
//
#include <hip/hip_runtime.h>

// MHA fused forward on gfx950.
// B=4, S=2048, E=2048, H=16, D=128; M = B*S = 8192.
// Outputs (concat in d_out): out (B,S,E) fp32 | k (B,H,S,D) fp32 | v (B,H,S,D) fp32.

typedef unsigned short u16;
typedef unsigned int   u32;
typedef float  f32x4  __attribute__((ext_vector_type(4)));
typedef __bf16 bf16x8 __attribute__((ext_vector_type(8)));

#define B_  4
#define S_  2048
#define E_  2048
#define H_  16
#define D_  128

__device__ __forceinline__ u16 f2bf(float f) {
    union { float f; u32 u; } v; v.f = f;
    return (u16)((v.u + 0x8000u) >> 16);          // round-half-up: cheap, <=0.5ulp+tiny bias
}
__device__ __forceinline__ u32 pack_bf(float a, float b) {
    union { float f; u32 u; } x, y; x.f = a; y.f = b;
    return ((x.u + 0x8000u) >> 16) | ((y.u + 0x8000u) & 0xFFFF0000u);
}
__device__ __forceinline__ float bf2f(u16 h) {
    union { u32 u; float f; } v; v.u = ((u32)h) << 16; return v.f;
}

// ---------------------------------------------------------------------------
// Transpose + convert: W (K x N, fp32 row-major) -> WT (N x K, bf16 row-major)
// ---------------------------------------------------------------------------
__global__ __launch_bounds__(256) void wtrans_kernel(
    const float* __restrict__ W, u16* __restrict__ WT, int K, int N)
{
    __shared__ float tile[64][65];                 // +1 pad: conflict-free transpose reads
    const int n0 = blockIdx.x * 64, k0 = blockIdx.y * 64;
    const int t = threadIdx.x;
#pragma unroll
    for (int i = 0; i < 16; ++i) {
        int idx = i * 256 + t; int r = idx >> 6, c = idx & 63;
        tile[r][c] = W[(size_t)(k0 + r) * N + n0 + c];
    }
    __syncthreads();
#pragma unroll
    for (int i = 0; i < 16; ++i) {
        int idx = i * 256 + t; int rn = idx >> 6, ck = idx & 63;
        WT[(size_t)(n0 + rn) * K + k0 + ck] = f2bf(tile[ck][rn]);
    }
}

// ---------------------------------------------------------------------------
// GEMM core: C = A (M x K) * Bt^T (Bt is N x K bf16), 128x128x32 tiles,
// 256 thr = 4 waves, each wave 64x64 via 4x4 mfma_f32_16x16x32_bf16.
// MODE 0: A fp32 (=x), epilogue scatters q/k bf16, v fp32+V^T bf16.
// MODE 1: A bf16 (=y), epilogue writes fp32 out + bias.
// ---------------------------------------------------------------------------
template <int MODE>
__global__ __launch_bounds__(256) void gemm_kernel(
    const void* __restrict__ Av, const u16* __restrict__ Bt,
    const float* __restrict__ bias,
    u16* __restrict__ qh, u16* __restrict__ kh, u16* __restrict__ vt,
    float* __restrict__ vout, float* __restrict__ outf,
    int N, int K)
{
    constexpr int LDT = 40;                        // padded LDS stride (bf16): 80B rows, 2-way max
    __shared__ u16 As[128 * LDT];
    __shared__ u16 Bs[128 * LDT];

    const int t = threadIdx.x;
    const int wave = t >> 6, lane = t & 63, quad = lane >> 4, l16 = lane & 15;
    const int wr = wave >> 1, wc = wave & 1;
    const int m0 = blockIdx.y * 128, n0 = blockIdx.x * 128;

    f32x4 acc[4][4] = {};

    const int c0 = t, c1 = t + 256;
    const int rA0 = c0 >> 2, kA0 = (c0 & 3) * 8;
    const int rA1 = c1 >> 2, kA1 = (c1 & 3) * 8;

    for (int k0 = 0; k0 < K; k0 += 32) {
        if constexpr (MODE == 0) {
            const float* A = (const float*)Av;
#pragma unroll
            for (int cc = 0; cc < 2; ++cc) {
                int row = cc ? rA1 : rA0, kc = cc ? kA1 : kA0;
                const float* src = A + (size_t)(m0 + row) * K + k0 + kc;
                float4 a0 = *(const float4*)src;
                float4 a1 = *(const float4*)(src + 4);
                uint4 pk;
                pk.x = pack_bf(a0.x, a0.y); pk.y = pack_bf(a0.z, a0.w);
                pk.z = pack_bf(a1.x, a1.y); pk.w = pack_bf(a1.z, a1.w);
                *(uint4*)(As + row * LDT + kc) = pk;
            }
        } else {
            const u16* A = (const u16*)Av;
#pragma unroll
            for (int cc = 0; cc < 2; ++cc) {
                int row = cc ? rA1 : rA0, kc = cc ? kA1 : kA0;
                *(uint4*)(As + row * LDT + kc) =
                    *(const uint4*)(A + (size_t)(m0 + row) * K + k0 + kc);
            }
        }
#pragma unroll
        for (int cc = 0; cc < 2; ++cc) {
            int row = cc ? rA1 : rA0, kc = cc ? kA1 : kA0;
            *(uint4*)(Bs + row * LDT + kc) =
                *(const uint4*)(Bt + (size_t)(n0 + row) * K + k0 + kc);
        }
        __syncthreads();

        bf16x8 af[4], bfr[4];
#pragma unroll
        for (int mi = 0; mi < 4; ++mi)
            af[mi] = *(const bf16x8*)(As + (wr * 64 + mi * 16 + l16) * LDT + quad * 8);
#pragma unroll
        for (int ni = 0; ni < 4; ++ni)
            bfr[ni] = *(const bf16x8*)(Bs + (wc * 64 + ni * 16 + l16) * LDT + quad * 8);
#pragma unroll
        for (int mi = 0; mi < 4; ++mi)
#pragma unroll
            for (int ni = 0; ni < 4; ++ni)
                acc[mi][ni] = __builtin_amdgcn_mfma_f32_16x16x32_bf16(
                    af[mi], bfr[ni], acc[mi][ni], 0, 0, 0);
        __syncthreads();
    }

    if constexpr (MODE == 0) {
        // block-uniform: 128-col tile lies in exactly one of q/k/v and one head
        const int sel = n0 >> 11;                  // 0=q 1=k 2=v
        const int h   = (n0 & 2047) >> 7;
        const int b   = m0 >> 11, sb = m0 & 2047;
        const size_t hb = ((size_t)(b * H_ + h)) * S_ * D_;
#pragma unroll
        for (int mi = 0; mi < 4; ++mi) {
            int s0 = sb + wr * 64 + mi * 16 + quad * 4;
#pragma unroll
            for (int ni = 0; ni < 4; ++ni) {
                int d = wc * 64 + ni * 16 + l16;
                float bv = bias[n0 + d];
                float v0 = acc[mi][ni][0] + bv, v1 = acc[mi][ni][1] + bv;
                float v2 = acc[mi][ni][2] + bv, v3 = acc[mi][ni][3] + bv;
                size_t base = hb + (size_t)s0 * D_ + d;
                if (sel < 2) {
                    u16* dst = sel ? kh : qh;
                    dst[base]       = f2bf(v0); dst[base + D_]     = f2bf(v1);
                    dst[base + 2*D_] = f2bf(v2); dst[base + 3*D_]  = f2bf(v3);
                } else {
                    vout[base] = v0; vout[base + D_] = v1;
                    vout[base + 2*D_] = v2; vout[base + 3*D_] = v3;
                    // V^T (b,h,d,s) bf16: reg index r = consecutive s -> 8B packed store
                    uint2 pk; pk.x = pack_bf(v0, v1); pk.y = pack_bf(v2, v3);
                    *(uint2*)(vt + ((size_t)(b * H_ + h) * D_ + d) * S_ + s0) = pk;
                }
            }
        }
    } else {
#pragma unroll
        for (int mi = 0; mi < 4; ++mi) {
            int row0 = m0 + wr * 64 + mi * 16 + quad * 4;
#pragma unroll
            for (int ni = 0; ni < 4; ++ni) {
                int col = n0 + wc * 64 + ni * 16 + l16;
                float bv = bias[col];
#pragma unroll
                for (int r = 0; r < 4; ++r)
                    outf[(size_t)(row0 + r) * N + col] = acc[mi][ni][r] + bv;
            }
        }
    }
}

// ---------------------------------------------------------------------------
// Rotary: in-place on qh/kh (bf16, head layout), k fp32 -> d_out.
// Folds 1/sqrt(D) into q. 8 contiguous d per thread (4 rotary pairs).
// ---------------------------------------------------------------------------
__global__ __launch_bounds__(256) void rotary_kernel(
    u16* __restrict__ q, u16* __restrict__ k, float* __restrict__ kout,
    const float* __restrict__ cosT, const float* __restrict__ sinT)
{
    const int g = blockIdx.x * 256 + threadIdx.x;  // B*H*S*D/8 threads
    const int d0 = (g & 15) << 3;
    const int srow = g >> 4;
    const int s = srow & (S_ - 1);
    const size_t base = (size_t)srow * D_ + d0;

    uint4 qv = *(const uint4*)(q + base);
    uint4 kv = *(const uint4*)(k + base);
    float cc[8], ss[8];
    *(float4*)(cc)     = *(const float4*)(cosT + s * D_ + d0);
    *(float4*)(cc + 4) = *(const float4*)(cosT + s * D_ + d0 + 4);
    *(float4*)(ss)     = *(const float4*)(sinT + s * D_ + d0);
    *(float4*)(ss + 4) = *(const float4*)(sinT + s * D_ + d0 + 4);
    const u16* qp = (const u16*)&qv; const u16* kp = (const u16*)&kv;
    float qo[8], ko[8];
#pragma unroll
    for (int i = 0; i < 4; ++i) {
        float q1 = bf2f(qp[2*i]), q2 = bf2f(qp[2*i+1]);
        float k1 = bf2f(kp[2*i]), k2 = bf2f(kp[2*i+1]);
        qo[2*i]   = q1 * cc[2*i]   - q2 * ss[2*i];
        qo[2*i+1] = q2 * cc[2*i+1] + q1 * ss[2*i+1];
        ko[2*i]   = k1 * cc[2*i]   - k2 * ss[2*i];
        ko[2*i+1] = k2 * cc[2*i+1] + k1 * ss[2*i+1];
    }
    const float qs_ = 0.08838834764831845f;        // 1/sqrt(128) folded into q
    uint4 qpk, kpk;
    u32* qq = (u32*)&qpk; u32* kq = (u32*)&kpk;
#pragma unroll
    for (int i = 0; i < 4; ++i) {
        qq[i] = pack_bf(qo[2*i] * qs_, qo[2*i+1] * qs_);
        kq[i] = pack_bf(ko[2*i], ko[2*i+1]);
    }
    *(uint4*)(q + base) = qpk;
    *(uint4*)(k + base) = kpk;
    *(float4*)(kout + base)     = make_float4(ko[0], ko[1], ko[2], ko[3]);
    *(float4*)(kout + base + 4) = make_float4(ko[4], ko[5], ko[6], ko[7]);
}

// ---------------------------------------------------------------------------
// Flash attention: Br=64 (wave = 16 q-rows), Bc=128, 16x16x32 bf16 MFMA.
// Q/K swizzled LDS; V^T tile from pre-transposed vt; P reuses the K buffer.
// XOR-chunk swizzle (c ^ (row&7)) keeps every b128 access <=2-way.
// ---------------------------------------------------------------------------
#define SWZ(row, c) ((row) * 128 + ((((c) ^ ((row) & 7))) << 3))

__global__ __launch_bounds__(256) void attn_kernel(
    const u16* __restrict__ qh, const u16* __restrict__ kh,
    const u16* __restrict__ vt, u16* __restrict__ yb)
{
    __shared__ u16 Qs[64 * 128];
    __shared__ u16 Ks[128 * 128];                  // doubles as P (rows 0..63 used)
    __shared__ u16 Vs[128 * 128];                  // V^T tile: [d][key]

    const int t = threadIdx.x, wave = t >> 6, lane = t & 63;
    const int quad = lane >> 4, l16 = lane & 15;
    const int bh = blockIdx.y, q0 = blockIdx.x * 64;
    const u16* qb = qh + ((size_t)bh * S_ + q0) * D_;
    const u16* kb = kh + (size_t)bh * S_ * D_;
    const u16* vb = vt + (size_t)bh * D_ * S_;

#pragma unroll
    for (int i = 0; i < 4; ++i) {
        int id = i * 256 + t, row = id >> 4, c = id & 15;
        *(uint4*)(Qs + SWZ(row, c)) = *(const uint4*)(qb + row * D_ + (c << 3));
    }
    __syncthreads();
    bf16x8 qf[4];
#pragma unroll
    for (int kk = 0; kk < 4; ++kk) {
        int row = wave * 16 + l16, c = kk * 4 + quad;
        qf[kk] = *(const bf16x8*)(Qs + SWZ(row, c));
    }

    f32x4 o[8] = {};
    float m_r[4] = {-1e30f, -1e30f, -1e30f, -1e30f};
    float l_r[4] = {0.f, 0.f, 0.f, 0.f};

    for (int k0 = 0; k0 < S_; k0 += 128) {
        __syncthreads();                           // prior iter's P/V reads done
#pragma unroll
        for (int i = 0; i < 8; ++i) {
            int id = i * 256 + t, row = id >> 4, c = id & 15;
            int sw = SWZ(row, c);
            *(uint4*)(Ks + sw) = *(const uint4*)(kb + (size_t)(k0 + row) * D_ + (c << 3));
            *(uint4*)(Vs + sw) = *(const uint4*)(vb + (size_t)row * S_ + k0 + (c << 3));
        }
        __syncthreads();

        f32x4 sc[8] = {};
#pragma unroll
        for (int kk = 0; kk < 4; ++kk) {
#pragma unroll
            for (int nt = 0; nt < 8; ++nt) {
                int row = nt * 16 + l16, c = kk * 4 + quad;
                bf16x8 kf = *(const bf16x8*)(Ks + SWZ(row, c));
                sc[nt] = __builtin_amdgcn_mfma_f32_16x16x32_bf16(qf[kk], kf, sc[nt], 0, 0, 0);
            }
        }
        // online softmax (scale pre-folded into q)
        float alpha[4];
#pragma unroll
        for (int r = 0; r < 4; ++r) {
            float mx = sc[0][r];
#pragma unroll
            for (int nt = 1; nt < 8; ++nt) mx = fmaxf(mx, sc[nt][r]);
#pragma unroll
            for (int off = 1; off < 16; off <<= 1) mx = fmaxf(mx, __shfl_xor(mx, off));
            float mn = fmaxf(m_r[r], mx);
            alpha[r] = __expf(m_r[r] - mn);
            m_r[r] = mn;
        }
        float rs[4] = {0.f, 0.f, 0.f, 0.f};
#pragma unroll
        for (int nt = 0; nt < 8; ++nt)
#pragma unroll
            for (int r = 0; r < 4; ++r) {
                float p = __expf(sc[nt][r] - m_r[r]);
                sc[nt][r] = p; rs[r] += p;
            }
#pragma unroll
        for (int r = 0; r < 4; ++r) {
#pragma unroll
            for (int off = 1; off < 16; off <<= 1) rs[r] += __shfl_xor(rs[r], off);
            l_r[r] = l_r[r] * alpha[r] + rs[r];
        }
#pragma unroll
        for (int dt = 0; dt < 8; ++dt)
#pragma unroll
            for (int r = 0; r < 4; ++r) o[dt][r] *= alpha[r];

        __syncthreads();                           // all waves done reading Ks
        // P (C-layout regs) -> LDS rows [wave*16, +16) of Ks (A-layout round-trip)
#pragma unroll
        for (int nt = 0; nt < 8; ++nt)
#pragma unroll
            for (int r = 0; r < 4; ++r) {
                int prow = wave * 16 + quad * 4 + r, col = nt * 16 + l16;
                Ks[SWZ(prow, (col >> 3)) + (col & 7)] = f2bf(sc[nt][r]);
            }
        // PV: o += P @ V   (own-wave P rows only -> no extra barrier)
#pragma unroll
        for (int kk2 = 0; kk2 < 4; ++kk2) {
            int prow = wave * 16 + l16, c = kk2 * 4 + quad;
            bf16x8 pf = *(const bf16x8*)(Ks + SWZ(prow, c));
#pragma unroll
            for (int dt = 0; dt < 8; ++dt) {
                int vrow = dt * 16 + l16;
                bf16x8 vf = *(const bf16x8*)(Vs + SWZ(vrow, c));
                o[dt] = __builtin_amdgcn_mfma_f32_16x16x32_bf16(pf, vf, o[dt], 0, 0, 0);
            }
        }
    }
    // epilogue: normalize, write y (b,s,h*D+d) bf16
    const int b = bh >> 4, h = bh & 15;
#pragma unroll
    for (int dt = 0; dt < 8; ++dt) {
        int d = h * D_ + dt * 16 + l16;
#pragma unroll
        for (int r = 0; r < 4; ++r) {
            int s = q0 + wave * 16 + quad * 4 + r;
            yb[(size_t)(b * S_ + s) * E_ + d] = f2bf(o[dt][r] / l_r[r]);
        }
    }
}

// ---------------------------------------------------------------------------
extern "C" void kernel_launch(void* const* d_in, const int* in_sizes, int n_in,
                              void* d_out, int out_size, void* d_ws, size_t ws_size,
                              hipStream_t stream)
{
    (void)in_sizes; (void)n_in; (void)out_size; (void)ws_size;
    const float* x     = (const float*)d_in[0];
    const float* cosT  = (const float*)d_in[1];
    const float* sinT  = (const float*)d_in[2];
    const float* Wqkv  = (const float*)d_in[3];
    const float* bqkv  = (const float*)d_in[4];
    const float* Wproj = (const float*)d_in[5];
    const float* bproj = (const float*)d_in[6];

    float* out  = (float*)d_out;                       // (B,S,E)
    float* kout = out  + (size_t)B_ * S_ * E_;         // (B,H,S,D)
    float* vout = kout + (size_t)B_ * S_ * E_;         // (B,H,S,D)

    // workspace (bf16 buffers), 160 MiB total
    u16* wqkvT  = (u16*)d_ws;                          // 6144 x 2048
    u16* wprojT = wqkvT  + (size_t)12582912;           // 2048 x 2048
    u16* qh     = wprojT + (size_t)4194304;            // (B,H,S,D)
    u16* kh     = qh     + (size_t)16777216;           // (B,H,S,D)
    u16* vt     = kh     + (size_t)16777216;           // (B,H,D,S)  V^T
    u16* yb     = vt     + (size_t)16777216;           // (B,S,E)

    wtrans_kernel<<<dim3(96, 32), 256, 0, stream>>>(Wqkv, wqkvT, 2048, 6144);
    wtrans_kernel<<<dim3(32, 32), 256, 0, stream>>>(Wproj, wprojT, 2048, 2048);
    gemm_kernel<0><<<dim3(48, 64), 256, 0, stream>>>(
        x, wqkvT, bqkv, qh, kh, vt, vout, nullptr, 6144, 2048);
    rotary_kernel<<<8192, 256, 0, stream>>>(qh, kh, kout, cosT, sinT);
    attn_kernel<<<dim3(32, 64), 256, 0, stream>>>(qh, kh, vt, yb);
    gemm_kernel<1><<<dim3(16, 64), 256, 0, stream>>>(
        yb, wprojT, bproj, nullptr, nullptr, nullptr, nullptr, out, 2048, 2048);
}

// Round 2
// 916.461 us; speedup vs baseline: 1.4715x; 1.4715x over previous
//
#include <hip/hip_runtime.h>

// MHA fused forward on gfx950.
// B=4, S=2048, E=2048, H=16, D=128; M = B*S = 8192.
// Outputs (concat in d_out): out (B,S,E) fp32 | k (B,H,S,D) fp32 | v (B,H,S,D) fp32.

typedef unsigned short u16;
typedef unsigned int   u32;
typedef float  f32x4  __attribute__((ext_vector_type(4)));
typedef __bf16 bf16x8 __attribute__((ext_vector_type(8)));

#define B_  4
#define S_  2048
#define E_  2048
#define H_  16
#define D_  128

__device__ __forceinline__ u16 f2bf(float f) {
    union { float f; u32 u; } v; v.f = f;
    return (u16)((v.u + 0x8000u) >> 16);
}
__device__ __forceinline__ u32 pack_bf(float a, float b) {
    union { float f; u32 u; } x, y; x.f = a; y.f = b;
    return ((x.u + 0x8000u) >> 16) | ((y.u + 0x8000u) & 0xFFFF0000u);
}
__device__ __forceinline__ float bf2f(u16 h) {
    union { u32 u; float f; } v; v.u = ((u32)h) << 16; return v.f;
}

// async global->LDS, 16B/lane. LDS dest = wave-uniform base + lane*16.
__device__ __forceinline__ void gld16(const u16* g, u16* l) {
    __builtin_amdgcn_global_load_lds(
        (const __attribute__((address_space(1))) void*)g,
        (__attribute__((address_space(3))) void*)l, 16, 0, 0);
}

// ---------------------------------------------------------------------------
// x (fp32) -> bf16, 8 elems/thread
// ---------------------------------------------------------------------------
__global__ __launch_bounds__(256) void xconv_kernel(
    const float* __restrict__ x, u16* __restrict__ xb)
{
    size_t g = (size_t)blockIdx.x * 256 + threadIdx.x;
    const float4* p = (const float4*)x + g * 2;
    float4 a = p[0], b = p[1];
    uint4 pk;
    pk.x = pack_bf(a.x, a.y); pk.y = pack_bf(a.z, a.w);
    pk.z = pack_bf(b.x, b.y); pk.w = pack_bf(b.z, b.w);
    ((uint4*)xb)[g] = pk;
}

// ---------------------------------------------------------------------------
// Transpose + convert: W (K x N fp32) -> WT (N x K bf16)
// ---------------------------------------------------------------------------
__global__ __launch_bounds__(256) void wtrans_kernel(
    const float* __restrict__ W, u16* __restrict__ WT, int K, int N)
{
    __shared__ float tile[64][65];
    const int n0 = blockIdx.x * 64, k0 = blockIdx.y * 64;
    const int t = threadIdx.x;
#pragma unroll
    for (int i = 0; i < 16; ++i) {
        int idx = i * 256 + t; int r = idx >> 6, c = idx & 63;
        tile[r][c] = W[(size_t)(k0 + r) * N + n0 + c];
    }
    __syncthreads();
#pragma unroll
    for (int i = 0; i < 16; ++i) {
        int idx = i * 256 + t; int rn = idx >> 6, ck = idx & 63;
        WT[(size_t)(n0 + rn) * K + k0 + ck] = f2bf(tile[ck][rn]);
    }
}

// ---------------------------------------------------------------------------
// GEMM: C = A (M x K bf16) * Bt^T (Bt N x K bf16). 128x128x32 tiles, m97-style
// global_load_lds staging, XOR-swizzled [128][4-chunk] LDS (2-way max).
// MODE 0: epilogue scatters q/k bf16, v fp32 + V^T bf16. MODE 1: fp32 out+bias.
// ---------------------------------------------------------------------------
template <int MODE>
__global__ __launch_bounds__(256) void gemm_kernel(
    const u16* __restrict__ A, const u16* __restrict__ Bt,
    const float* __restrict__ bias,
    u16* __restrict__ qh, u16* __restrict__ kh, u16* __restrict__ vt,
    float* __restrict__ vout, float* __restrict__ outf,
    int N, int K)
{
    __shared__ u16 As[128 * 32];
    __shared__ u16 Bs[128 * 32];

    const int t = threadIdx.x;
    const int wave = t >> 6, lane = t & 63, quad = lane >> 4, l16 = lane & 15;
    const int wr = wave >> 1, wc = wave & 1;
    const int m0 = blockIdx.y * 128, n0 = blockIdx.x * 128;

    f32x4 acc[4][4] = {};
    const int swr = (quad ^ ((l16 >> 1) & 3)) << 3;   // swizzled read chunk offset

    for (int k0 = 0; k0 < K; k0 += 32) {
        __syncthreads();
#pragma unroll
        for (int i = 0; i < 2; ++i) {
            int idx = i * 256 + t;
            int row = idx >> 2, c = (idx & 3) ^ ((row >> 1) & 3);
            gld16(A  + (size_t)(m0 + row) * K + k0 + (c << 3),
                  As + ((i * 256 + wave * 64) << 3));
            gld16(Bt + (size_t)(n0 + row) * K + k0 + (c << 3),
                  Bs + ((i * 256 + wave * 64) << 3));
        }
        __syncthreads();

        bf16x8 af[4], bfr[4];
#pragma unroll
        for (int mi = 0; mi < 4; ++mi)
            af[mi] = *(const bf16x8*)(As + (wr * 64 + mi * 16 + l16) * 32 + swr);
#pragma unroll
        for (int ni = 0; ni < 4; ++ni)
            bfr[ni] = *(const bf16x8*)(Bs + (wc * 64 + ni * 16 + l16) * 32 + swr);
#pragma unroll
        for (int mi = 0; mi < 4; ++mi)
#pragma unroll
            for (int ni = 0; ni < 4; ++ni)
                acc[mi][ni] = __builtin_amdgcn_mfma_f32_16x16x32_bf16(
                    af[mi], bfr[ni], acc[mi][ni], 0, 0, 0);
    }

    if constexpr (MODE == 0) {
        const int sel = n0 >> 11;                  // 0=q 1=k 2=v
        const int h   = (n0 & 2047) >> 7;
        const int b   = m0 >> 11, sb = m0 & 2047;
        const size_t hb = ((size_t)(b * H_ + h)) * S_ * D_;
#pragma unroll
        for (int mi = 0; mi < 4; ++mi) {
            int s0 = sb + wr * 64 + mi * 16 + quad * 4;
#pragma unroll
            for (int ni = 0; ni < 4; ++ni) {
                int d = wc * 64 + ni * 16 + l16;
                float bv = bias[n0 + d];
                float v0 = acc[mi][ni][0] + bv, v1 = acc[mi][ni][1] + bv;
                float v2 = acc[mi][ni][2] + bv, v3 = acc[mi][ni][3] + bv;
                size_t base = hb + (size_t)s0 * D_ + d;
                if (sel < 2) {
                    u16* dst = sel ? kh : qh;
                    dst[base]        = f2bf(v0); dst[base + D_]    = f2bf(v1);
                    dst[base + 2*D_] = f2bf(v2); dst[base + 3*D_]  = f2bf(v3);
                } else {
                    vout[base] = v0; vout[base + D_] = v1;
                    vout[base + 2*D_] = v2; vout[base + 3*D_] = v3;
                    uint2 pk; pk.x = pack_bf(v0, v1); pk.y = pack_bf(v2, v3);
                    *(uint2*)(vt + ((size_t)(b * H_ + h) * D_ + d) * S_ + s0) = pk;
                }
            }
        }
    } else {
#pragma unroll
        for (int mi = 0; mi < 4; ++mi) {
            int row0 = m0 + wr * 64 + mi * 16 + quad * 4;
#pragma unroll
            for (int ni = 0; ni < 4; ++ni) {
                int col = n0 + wc * 64 + ni * 16 + l16;
                float bv = bias[col];
#pragma unroll
                for (int r = 0; r < 4; ++r)
                    outf[(size_t)(row0 + r) * N + col] = acc[mi][ni][r] + bv;
            }
        }
    }
}

// ---------------------------------------------------------------------------
// Rotary: in-place on qh/kh (bf16), k fp32 -> d_out. Folds 1/sqrt(D)*log2(e)
// into q (softmax done in base-2).
// ---------------------------------------------------------------------------
__global__ __launch_bounds__(256) void rotary_kernel(
    u16* __restrict__ q, u16* __restrict__ k, float* __restrict__ kout,
    const float* __restrict__ cosT, const float* __restrict__ sinT)
{
    const int g = blockIdx.x * 256 + threadIdx.x;
    const int d0 = (g & 15) << 3;
    const int srow = g >> 4;
    const int s = srow & (S_ - 1);
    const size_t base = (size_t)srow * D_ + d0;

    uint4 qv = *(const uint4*)(q + base);
    uint4 kv = *(const uint4*)(k + base);
    float cc[8], ss[8];
    *(float4*)(cc)     = *(const float4*)(cosT + s * D_ + d0);
    *(float4*)(cc + 4) = *(const float4*)(cosT + s * D_ + d0 + 4);
    *(float4*)(ss)     = *(const float4*)(sinT + s * D_ + d0);
    *(float4*)(ss + 4) = *(const float4*)(sinT + s * D_ + d0 + 4);
    const u16* qp = (const u16*)&qv; const u16* kp = (const u16*)&kv;
    float qo[8], ko[8];
#pragma unroll
    for (int i = 0; i < 4; ++i) {
        float q1 = bf2f(qp[2*i]), q2 = bf2f(qp[2*i+1]);
        float k1 = bf2f(kp[2*i]), k2 = bf2f(kp[2*i+1]);
        qo[2*i]   = q1 * cc[2*i]   - q2 * ss[2*i];
        qo[2*i+1] = q2 * cc[2*i+1] + q1 * ss[2*i+1];
        ko[2*i]   = k1 * cc[2*i]   - k2 * ss[2*i];
        ko[2*i+1] = k2 * cc[2*i+1] + k1 * ss[2*i+1];
    }
    const float qs_ = 0.08838834764831845f * 1.4426950408889634f; // 1/sqrt(D)*log2e
    uint4 qpk, kpk;
    u32* qq = (u32*)&qpk; u32* kq = (u32*)&kpk;
#pragma unroll
    for (int i = 0; i < 4; ++i) {
        qq[i] = pack_bf(qo[2*i] * qs_, qo[2*i+1] * qs_);
        kq[i] = pack_bf(ko[2*i], ko[2*i+1]);
    }
    *(uint4*)(q + base) = qpk;
    *(uint4*)(k + base) = kpk;
    *(float4*)(kout + base)     = make_float4(ko[0], ko[1], ko[2], ko[3]);
    *(float4*)(kout + base + 4) = make_float4(ko[4], ko[5], ko[6], ko[7]);
}

// ---------------------------------------------------------------------------
// Flash attention. Br=64 (wave = 16 q-rows), Bc=64. S^T = K*Q^T so the C
// register index runs along keys -> packed b64 P-stores + 2-shuffle softmax.
// Q frags direct from global; K and V^T staged via global_load_lds into
// XOR-swizzled LDS; per-wave private P buffer (no 3rd barrier).
// LDS = 16+16+8 = 40 KB -> 4 blocks/CU.
// ---------------------------------------------------------------------------
#define KSWZ(row, c) ((row) * 128 + (((c) ^ ((row) & 7)) << 3))  // 64 x 16-chunk
#define VSWZ(d, c)   ((d) * 64 + (((c) ^ ((d) & 7)) << 3))       // 128 x 8-chunk
#define PSWZ(qr, c)  ((qr) * 64 + (((c) ^ ((qr) & 7)) << 3))     // 16 x 8-chunk

__global__ __launch_bounds__(256, 4) void attn_kernel(
    const u16* __restrict__ qh, const u16* __restrict__ kh,
    const u16* __restrict__ vt, u16* __restrict__ yb)
{
    __shared__ u16 Ks[64 * 128];        // 16 KB
    __shared__ u16 Vs[128 * 64];        // 16 KB  (V^T tile [d][key])
    __shared__ u16 Ps[4 * 16 * 64];     //  8 KB  (per-wave P [q][key])

    const int t = threadIdx.x, wave = t >> 6, lane = t & 63;
    const int quad = lane >> 4, l16 = lane & 15;
    const int bh = blockIdx.y, q0 = blockIdx.x * 64;
    const u16* kb = kh + (size_t)bh * S_ * D_;
    const u16* vb = vt + (size_t)bh * D_ * S_;
    u16* Pw = Ps + wave * (16 * 64);

    // Q fragments (B-operand layout: n=l16 q-row, k=quad*8) straight from global
    bf16x8 qf[4];
    {
        const u16* qp = qh + ((size_t)bh * S_ + q0 + wave * 16 + l16) * D_ + quad * 8;
#pragma unroll
        for (int kk = 0; kk < 4; ++kk) qf[kk] = *(const bf16x8*)(qp + kk * 32);
    }

    f32x4 o[8] = {};
    float m_r = -1e30f, l_r = 0.f;      // per-lane: q-row = l16 (replicated over quads)

    for (int k0 = 0; k0 < S_; k0 += 64) {
        __syncthreads();                // prior iter's LDS reads done
#pragma unroll
        for (int i = 0; i < 4; ++i) {
            int idx = i * 256 + t;
            {   // K rows [k0,k0+64) x 128d, swizzle folded into source chunk
                int row = idx >> 4, c = (idx & 15) ^ (row & 7);
                gld16(kb + (size_t)(k0 + row) * D_ + (c << 3),
                      Ks + ((i * 256 + wave * 64) << 3));
            }
            {   // V^T [128d][64 keys]
                int d = idx >> 3, c = (idx & 7) ^ (d & 7);
                gld16(vb + (size_t)d * S_ + k0 + (c << 3),
                      Vs + ((i * 256 + wave * 64) << 3));
            }
        }
        __syncthreads();

        // S^T tile: D[key][q] = K·Q^T ; A = K-frag, B = Q-frag
        f32x4 sc[4] = {};
#pragma unroll
        for (int kk = 0; kk < 4; ++kk) {
#pragma unroll
            for (int nt = 0; nt < 4; ++nt) {
                bf16x8 kf = *(const bf16x8*)(Ks + KSWZ(nt * 16 + l16, kk * 4 + quad));
                sc[nt] = __builtin_amdgcn_mfma_f32_16x16x32_bf16(kf, qf[kk], sc[nt], 0, 0, 0);
            }
        }
        // online softmax (base-2; scale folded into q). keys live on regs+quads.
        float mx = sc[0][0];
#pragma unroll
        for (int nt = 0; nt < 4; ++nt)
#pragma unroll
            for (int r = 0; r < 4; ++r) mx = fmaxf(mx, sc[nt][r]);
        mx = fmaxf(mx, __shfl_xor(mx, 16));
        mx = fmaxf(mx, __shfl_xor(mx, 32));
        float mn = fmaxf(m_r, mx);
        float alpha = exp2f(m_r - mn);
        m_r = mn;
        float rs = 0.f;
#pragma unroll
        for (int nt = 0; nt < 4; ++nt)
#pragma unroll
            for (int r = 0; r < 4; ++r) {
                float p = exp2f(sc[nt][r] - mn);
                sc[nt][r] = p; rs += p;
            }
        rs += __shfl_xor(rs, 16);
        rs += __shfl_xor(rs, 32);
        l_r = l_r * alpha + rs;
        // rescale o: its q-rows are quad*4+r -> broadcast alpha from lane quad*4+r
        float af4[4];
#pragma unroll
        for (int r = 0; r < 4; ++r) af4[r] = __shfl(alpha, quad * 4 + r);
#pragma unroll
        for (int dt = 0; dt < 8; ++dt)
#pragma unroll
            for (int r = 0; r < 4; ++r) o[dt][r] *= af4[r];

        // P store: lane's 4 acc values = 4 consecutive keys for q-row l16 -> b64
#pragma unroll
        for (int nt = 0; nt < 4; ++nt) {
            int key0 = nt * 16 + quad * 4;
            int chunk = key0 >> 3, sub = key0 & 7;     // sub = 0 or 4
            uint2 pk;
            pk.x = pack_bf(sc[nt][0], sc[nt][1]);
            pk.y = pack_bf(sc[nt][2], sc[nt][3]);
            *(uint2*)(Pw + PSWZ(l16, chunk) + sub) = pk;
        }
        // PV: O[q][d] += P·V ; A = P-frag (m=q), B = V^T-frag (n=d)
#pragma unroll
        for (int kk2 = 0; kk2 < 2; ++kk2) {
            bf16x8 pf = *(const bf16x8*)(Pw + PSWZ(l16, kk2 * 4 + quad));
#pragma unroll
            for (int dt = 0; dt < 8; ++dt) {
                bf16x8 vf = *(const bf16x8*)(Vs + VSWZ(dt * 16 + l16, kk2 * 4 + quad));
                o[dt] = __builtin_amdgcn_mfma_f32_16x16x32_bf16(pf, vf, o[dt], 0, 0, 0);
            }
        }
    }
    // epilogue: o rows are q=quad*4+r; l lives at lane l16=q -> broadcast
    float lf[4];
#pragma unroll
    for (int r = 0; r < 4; ++r) {
        float lv = __shfl(l_r, quad * 4 + r);
        lf[r] = __builtin_amdgcn_rcpf(lv);
    }
    const int b = bh >> 4, h = bh & 15;
#pragma unroll
    for (int dt = 0; dt < 8; ++dt) {
        int d = h * D_ + dt * 16 + l16;
#pragma unroll
        for (int r = 0; r < 4; ++r) {
            int s = q0 + wave * 16 + quad * 4 + r;
            yb[(size_t)(b * S_ + s) * E_ + d] = f2bf(o[dt][r] * lf[r]);
        }
    }
}

// ---------------------------------------------------------------------------
extern "C" void kernel_launch(void* const* d_in, const int* in_sizes, int n_in,
                              void* d_out, int out_size, void* d_ws, size_t ws_size,
                              hipStream_t stream)
{
    (void)in_sizes; (void)n_in; (void)out_size; (void)ws_size;
    const float* x     = (const float*)d_in[0];
    const float* cosT  = (const float*)d_in[1];
    const float* sinT  = (const float*)d_in[2];
    const float* Wqkv  = (const float*)d_in[3];
    const float* bqkv  = (const float*)d_in[4];
    const float* Wproj = (const float*)d_in[5];
    const float* bproj = (const float*)d_in[6];

    float* out  = (float*)d_out;                       // (B,S,E)
    float* kout = out  + (size_t)B_ * S_ * E_;         // (B,H,S,D)
    float* vout = kout + (size_t)B_ * S_ * E_;         // (B,H,S,D)

    u16* wqkvT  = (u16*)d_ws;                          // 6144 x 2048
    u16* wprojT = wqkvT  + (size_t)12582912;           // 2048 x 2048
    u16* qh     = wprojT + (size_t)4194304;            // (B,H,S,D)
    u16* kh     = qh     + (size_t)16777216;           // (B,H,S,D)
    u16* vt     = kh     + (size_t)16777216;           // (B,H,D,S)  V^T
    u16* yb     = vt     + (size_t)16777216;           // (B,S,E); doubles as xb
    u16* xb     = yb;                                  // x-bf16 dead before y written

    xconv_kernel<<<8192, 256, 0, stream>>>(x, xb);
    wtrans_kernel<<<dim3(96, 32), 256, 0, stream>>>(Wqkv, wqkvT, 2048, 6144);
    wtrans_kernel<<<dim3(32, 32), 256, 0, stream>>>(Wproj, wprojT, 2048, 2048);
    gemm_kernel<0><<<dim3(48, 64), 256, 0, stream>>>(
        xb, wqkvT, bqkv, qh, kh, vt, vout, nullptr, 6144, 2048);
    rotary_kernel<<<8192, 256, 0, stream>>>(qh, kh, kout, cosT, sinT);
    attn_kernel<<<dim3(32, 64), 256, 0, stream>>>(qh, kh, vt, yb);
    gemm_kernel<1><<<dim3(16, 64), 256, 0, stream>>>(
        yb, wprojT, bproj, nullptr, nullptr, nullptr, nullptr, out, 2048, 2048);
}